// Round 1
// baseline (406.647 us; speedup 1.0000x reference)
//
#include <hip/hip_runtime.h>
#include <hip/hip_cooperative_groups.h>
#include <math.h>

namespace cg = cooperative_groups;

#define B_ 4
#define S_ 4096
#define H_ 1024
#define NH 16
#define DH 64
#define CTX 128
#define CSTART (S_ - CTX)   // 3968
#define KDIM 1024
#define KH 512              // split-K half for QKV gemm

typedef __attribute__((ext_vector_type(8))) short short8;
typedef __attribute__((ext_vector_type(4))) float floatx4;
typedef unsigned short ushort_t;

__device__ inline unsigned short f2bf(float x) {
    union { float f; unsigned u; } v; v.f = x;
    unsigned r = v.u + 0x7fffu + ((v.u >> 16) & 1u);   // RNE
    return (unsigned short)(r >> 16);
}

__device__ inline uint4 pack8(float4 a, float4 b) {
    union { unsigned short us[8]; uint4 u4; } p;
    p.us[0]=f2bf(a.x); p.us[1]=f2bf(a.y); p.us[2]=f2bf(a.z); p.us[3]=f2bf(a.w);
    p.us[4]=f2bf(b.x); p.us[5]=f2bf(b.y); p.us[6]=f2bf(b.z); p.us[7]=f2bf(b.w);
    return p.u4;
}

__device__ inline float4 add4(float4 a, float4 b) {
    float4 r; r.x=a.x+b.x; r.y=a.y+b.y; r.z=a.z+b.z; r.w=a.w+b.w; return r;
}

#define GLOAD_LDS16(g, l) \
    __builtin_amdgcn_global_load_lds((__attribute__((address_space(1))) const void*)(g), \
                                     (__attribute__((address_space(3))) void*)(l), 16, 0, 0)

// ---------- 64x64 bf16 MFMA GEMM tile (XOR-swizzled LDS, global_load_lds 16B) ----------
// DIRECT=false: store fp32 to P[(row)*N + col] (P already offset to the split-K partial)
// DIRECT=true : store fp32 to out rows (row>>7)*S_ + CSTART + (row&127)  (ld = 1024)
template<bool DIRECT, int KLEN>
__device__ __forceinline__ void gemm_tile(const ushort_t* __restrict__ A,
                                          const ushort_t* __restrict__ W,
                                          float* __restrict__ P, int N,
                                          int m0, int n0, int koff,
                                          char* smem, int tid) {
    ushort_t* As = (ushort_t*)smem;          // [64][64]
    ushort_t* Bs = As + 4096;                // [64][64]
    int lane = tid & 63, w = tid >> 6;
    int f0 = tid, f1 = tid + 256;
    int r0 = f0 >> 3, g0 = (f0 & 7) ^ (r0 & 7);
    int r1 = f1 >> 3, g1 = (f1 & 7) ^ (r1 & 7);
    const ushort_t* ga0 = A + (size_t)(m0 + r0) * KDIM + koff + g0 * 8;
    const ushort_t* ga1 = A + (size_t)(m0 + r1) * KDIM + koff + g1 * 8;
    const ushort_t* gb0 = W + (size_t)(n0 + r0) * KDIM + koff + g0 * 8;
    const ushort_t* gb1 = W + (size_t)(n0 + r1) * KDIM + koff + g1 * 8;
    char* la0 = smem + f0 * 16;
    char* la1 = smem + f1 * 16;
    char* lb0 = smem + 8192 + f0 * 16;
    char* lb1 = smem + 8192 + f1 * 16;
    int fm = lane & 15, q = lane >> 4;
    int wr = w >> 1, wc = w & 1;
    int ma0 = wr * 32, na0 = wc * 32;
    floatx4 acc[2][2] = {};
    #pragma unroll
    for (int k0 = 0; k0 < KLEN; k0 += 64) {
        GLOAD_LDS16(ga0 + k0, la0);
        GLOAD_LDS16(ga1 + k0, la1);
        GLOAD_LDS16(gb0 + k0, lb0);
        GLOAD_LDS16(gb1 + k0, lb1);
        __syncthreads();
        #pragma unroll
        for (int kb = 0; kb < 2; kb++) {
            short8 af[2], bfr[2];
            #pragma unroll
            for (int t = 0; t < 2; t++) {
                int m = ma0 + t * 16 + fm;
                int pa = (kb * 4 + q) ^ (m & 7);
                af[t] = *(const short8*)(As + m * 64 + pa * 8);
                int n = na0 + t * 16 + fm;
                int pb = (kb * 4 + q) ^ (n & 7);
                bfr[t] = *(const short8*)(Bs + n * 64 + pb * 8);
            }
            #pragma unroll
            for (int i = 0; i < 2; i++)
                #pragma unroll
                for (int j = 0; j < 2; j++)
                    acc[i][j] = __builtin_amdgcn_mfma_f32_16x16x32_bf16(af[i], bfr[j], acc[i][j], 0, 0, 0);
        }
        __syncthreads();
    }
    #pragma unroll
    for (int i = 0; i < 2; i++)
        #pragma unroll
        for (int j = 0; j < 2; j++) {
            int row = m0 + ma0 + i * 16 + q * 4;
            int col = n0 + na0 + j * 16 + fm;
            #pragma unroll
            for (int t = 0; t < 4; t++) {
                int rr = row + t;
                if (DIRECT) {
                    size_t gr = (size_t)((rr >> 7) * S_ + CSTART + (rr & 127));
                    P[gr * 1024 + col] = acc[i][j][t];
                } else {
                    P[(size_t)rr * N + col] = acc[i][j][t];
                }
            }
        }
}

// ---------- MFMA attention body (verified): block = (b, h, half), 256 threads ----------
__device__ __forceinline__ void attn_body(const float* __restrict__ Pq,   // [2][512][3072]
                                          const int* __restrict__ amask,
                                          ushort_t* __restrict__ AO,
                                          char* smem, int gid) {
    ushort_t* Qs   = (ushort_t*)(smem);             // [64][72]
    ushort_t* Ksh  = (ushort_t*)(smem + 9216);      // [128][72]
    ushort_t* Pb   = (ushort_t*)(smem);             // overlay, [64 local rows][136]
    float*    linv = (float*)(smem + 27648);        // [64]
    int*      amk  = (int*)(smem + 27904);          // [128]
    ushort_t* Vt   = (ushort_t*)(smem + 28416);     // [64 dims][136 ctx]

    int b = gid >> 5, h = (gid >> 1) & 15, half = gid & 1;
    int tid = threadIdx.x;
    int cmax = half ? CTX : 64;
    {
        int r = tid >> 2, ch = tid & 3;
        size_t qb = (size_t)(b * CTX + half * 64 + r) * 3072 + h * 64 + ch * 16;
        const float4* q0 = (const float4*)(Pq + qb);
        const float4* q1 = (const float4*)(Pq + (size_t)512 * 3072 + qb);
        float4 a0 = add4(q0[0], q1[0]), a1 = add4(q0[1], q1[1]);
        float4 a2 = add4(q0[2], q1[2]), a3 = add4(q0[3], q1[3]);
        *(uint4*)(Qs + r * 72 + ch * 16)     = pack8(a0, a1);
        *(uint4*)(Qs + r * 72 + ch * 16 + 8) = pack8(a2, a3);
        for (int idx = tid; idx < cmax * 4; idx += 256) {
            int kr = idx >> 2, kch = idx & 3;
            size_t base = (size_t)(b * CTX + kr) * 3072 + h * 64 + kch * 16;
            const float4* p0 = (const float4*)(Pq + base);
            const float4* p1 = (const float4*)(Pq + (size_t)512 * 3072 + base);
            float4 k0 = add4(p0[256], p1[256]), k1 = add4(p0[257], p1[257]);
            float4 k2 = add4(p0[258], p1[258]), k3 = add4(p0[259], p1[259]);
            *(uint4*)(Ksh + kr * 72 + kch * 16)     = pack8(k0, k1);
            *(uint4*)(Ksh + kr * 72 + kch * 16 + 8) = pack8(k2, k3);
            float vv[16];
            #pragma unroll
            for (int c4 = 0; c4 < 4; c4++) {
                float4 s = add4(p0[512 + c4], p1[512 + c4]);
                vv[c4*4+0]=s.x; vv[c4*4+1]=s.y; vv[c4*4+2]=s.z; vv[c4*4+3]=s.w;
            }
            #pragma unroll
            for (int i = 0; i < 16; i++)
                Vt[(kch * 16 + i) * 136 + kr] = f2bf(vv[i]);
        }
        if (tid < 128) amk[tid] = amask[b * S_ + CSTART + tid];
    }
    __syncthreads();

    int w = tid >> 6, lane = tid & 63;
    int qt = half * 4 + w;
    int lr0 = w * 16;
    int fm = lane & 15, quad = lane >> 4;

    short8 af[2];
    #pragma unroll
    for (int kb = 0; kb < 2; kb++)
        af[kb] = *(const short8*)(Qs + (lr0 + fm) * 72 + kb * 32 + quad * 8);
    floatx4 acc[8] = {};
    for (int ct = 0; ct <= qt; ct++) {
        #pragma unroll
        for (int kb = 0; kb < 2; kb++) {
            short8 bfr = *(const short8*)(Ksh + (ct * 16 + fm) * 72 + kb * 32 + quad * 8);
            acc[ct] = __builtin_amdgcn_mfma_f32_16x16x32_bf16(af[kb], bfr, acc[ct], 0, 0, 0);
        }
    }
    int myamk[8];
    #pragma unroll
    for (int ct = 0; ct < 8; ct++) myamk[ct] = amk[ct * 16 + fm];
    float ls[4];
    #pragma unroll
    for (int t = 0; t < 4; t++) {
        int row = qt * 16 + quad * 4 + t;
        float m = -INFINITY;
        #pragma unroll
        for (int ct = 0; ct < 8; ct++) {
            int col = ct * 16 + fm;
            float s = acc[ct][t] * 0.125f;
            bool valid = (ct <= qt) && (col <= row) && (myamk[ct] != 0);
            if (valid) m = fmaxf(m, s);
        }
        #pragma unroll
        for (int off = 8; off >= 1; off >>= 1) m = fmaxf(m, __shfl_xor(m, off, 64));
        float l = 0.f;
        #pragma unroll
        for (int ct = 0; ct < 8; ct++) {
            int col = ct * 16 + fm;
            float s = acc[ct][t] * 0.125f;
            bool valid = (ct <= qt) && (col <= row) && (myamk[ct] != 0);
            float p = valid ? __expf(s - m) : 0.f;
            acc[ct][t] = p;
            l += p;
        }
        #pragma unroll
        for (int off = 8; off >= 1; off >>= 1) l += __shfl_xor(l, off, 64);
        ls[t] = l;
    }
    __syncthreads();
    #pragma unroll
    for (int t = 0; t < 4; t++) {
        int lrow = lr0 + quad * 4 + t;
        #pragma unroll
        for (int ct = 0; ct < 8; ct++)
            Pb[lrow * 136 + ct * 16 + fm] = f2bf(acc[ct][t]);
        if (fm == 0) linv[lrow] = 1.f / ls[t];
    }
    int kmax = (qt >> 1) + 1;
    floatx4 oacc[4] = {};
    for (int kb = 0; kb < kmax; kb++) {
        short8 paf = *(const short8*)(Pb + (lr0 + fm) * 136 + kb * 32 + quad * 8);
        #pragma unroll
        for (int dt = 0; dt < 4; dt++) {
            short8 vbf = *(const short8*)(Vt + (dt * 16 + fm) * 136 + kb * 32 + quad * 8);
            oacc[dt] = __builtin_amdgcn_mfma_f32_16x16x32_bf16(paf, vbf, oacc[dt], 0, 0, 0);
        }
    }
    #pragma unroll
    for (int t = 0; t < 4; t++) {
        int lrow = lr0 + quad * 4 + t;
        int grow = qt * 16 + quad * 4 + t;
        float inv = linv[lrow];
        #pragma unroll
        for (int dt = 0; dt < 4; dt++)
            AO[(size_t)(b * CTX + grow) * H_ + h * 64 + dt * 16 + fm] = f2bf(oacc[dt][t] * inv);
    }
}

// ---------- fused cooperative kernel: prep | QKV gemm | attn | O gemm | broadcast ----------
__global__ __launch_bounds__(256, 2) void fused(const float* __restrict__ in,
                                                const int* __restrict__ amask,
                                                const float* __restrict__ Wq, const float* __restrict__ Wk,
                                                const float* __restrict__ Wv, const float* __restrict__ Wo,
                                                ushort_t* __restrict__ Wbf, ushort_t* __restrict__ Xs,
                                                float* __restrict__ Pq, ushort_t* __restrict__ AObf,
                                                float* __restrict__ out) {
    __shared__ __align__(16) char smem[46080];
    cg::grid_group grid = cg::this_grid();
    int bid = blockIdx.x, tid = threadIdx.x;

    // ---- P1: weights fp32->bf16 (4M elems) + gather/convert x slice (512K elems) ----
    for (unsigned u = (unsigned)bid * 256 + tid; u < 589824u; u += 131072u) {
        size_t e = (size_t)u * 8;
        if (u < 524288u) {
            int wsel = (int)(e >> 20);
            size_t off = e & 1048575;
            const float* src = wsel == 0 ? Wq : wsel == 1 ? Wk : wsel == 2 ? Wv : Wo;
            const float4* s4 = (const float4*)(src + off);
            *(uint4*)(Wbf + e) = pack8(s4[0], s4[1]);
        } else {
            size_t e2 = e - 4194304;
            int m = (int)(e2 >> 10), col = (int)(e2 & 1023);
            int b2 = m >> 7, i = m & 127;
            const float4* s4 = (const float4*)(in + (size_t)(b2 * S_ + CSTART + i) * H_ + col);
            *(uint4*)(Xs + e2) = pack8(s4[0], s4[1]);
        }
    }
    grid.sync();

    // ---- P2: QKV gemm, 768 jobs (48 x 8 x 2 split-K), blocks 0..255 take a 2nd job ----
    {
        int job = bid;
        int x = job % 48, y = (job / 48) & 7, z = job / 384;
        gemm_tile<false, KH>(Xs, Wbf, Pq + (size_t)z * 512 * 3072, 3072,
                             y * 64, x * 64, z * KH, smem, tid);
        if (bid < 256) {
            int j2 = bid + 512;
            int x2 = j2 % 48, y2 = (j2 / 48) & 7, z2 = j2 / 384;
            gemm_tile<false, KH>(Xs, Wbf, Pq + (size_t)z2 * 512 * 3072, 3072,
                                 y2 * 64, x2 * 64, z2 * KH, smem, tid);
        }
    }
    grid.sync();

    // ---- P3: attention, 128 jobs ----
    if (bid < 128) attn_body(Pq, amask, AObf, smem, bid);
    grid.sync();

    // ---- P4: O gemm, non-split K=1024, 128 jobs (8 x 16), direct store to out rows ----
    if (bid < 128) {
        int x = bid % 16, y = bid / 16;
        gemm_tile<true, 1024>(AObf, Wbf + (size_t)3072 * 1024, out, 1024,
                              y * 64, x * 64, 0, smem, tid);
    }
    grid.sync();

    // ---- P5: broadcast out row CSTART into rows 0..CSTART-1 (per batch) ----
    // total float4 units: 4 * 3968 * 256 = 4063232
    for (unsigned idx = (unsigned)bid * 256 + tid; idx < 4063232u; idx += 131072u) {
        unsigned b2 = idx / 1015808u;           // 3968*256
        unsigned rem = idx - b2 * 1015808u;
        unsigned p = rem >> 8;                  // 0..3967
        unsigned c4 = rem & 255u;
        float4 v = *(const float4*)(out + (size_t)(b2 * S_ + CSTART) * H_ + c4 * 4);
        ((float4*)out)[(size_t)(b2 * S_ + p) * 256 + c4] = v;
    }
}

extern "C" void kernel_launch(void* const* d_in, const int* in_sizes, int n_in,
                              void* d_out, int out_size, void* d_ws, size_t ws_size,
                              hipStream_t stream) {
    const float* inputs = (const float*)d_in[0];
    const int*   amask  = (const int*)d_in[1];
    const float* Wq     = (const float*)d_in[2];
    const float* Wk     = (const float*)d_in[3];
    const float* Wv     = (const float*)d_in[4];
    const float* Wo     = (const float*)d_in[5];
    float* out = (float*)d_out;

    char* ws = (char*)d_ws;
    ushort_t* Xs   = (ushort_t*)(ws);                 // 1 MB
    ushort_t* Wbf  = (ushort_t*)(ws + (1u << 20));    // 8 MB (Wq|Wk|Wv|Wo)
    float*    Pq   = (float*)(ws + (9u << 20));       // 12.6 MB [2][512][3072] fp32
    ushort_t* AObf = (ushort_t*)(ws + (23u << 20));   // 1 MB [512][1024] bf16

    void* args[11];
    args[0]  = (void*)&inputs;
    args[1]  = (void*)&amask;
    args[2]  = (void*)&Wq;
    args[3]  = (void*)&Wk;
    args[4]  = (void*)&Wv;
    args[5]  = (void*)&Wo;
    args[6]  = (void*)&Wbf;
    args[7]  = (void*)&Xs;
    args[8]  = (void*)&Pq;
    args[9]  = (void*)&AObf;
    args[10] = (void*)&out;

    hipLaunchCooperativeKernel((const void*)fused, dim3(512), dim3(256), args, 0, stream);
}

// Round 2
// 155.779 us; speedup vs baseline: 2.6104x; 2.6104x over previous
//
#include <hip/hip_runtime.h>
#include <math.h>

#define B_ 4
#define S_ 4096
#define H_ 1024
#define NH 16
#define DH 64
#define CTX 128
#define CSTART (S_ - CTX)   // 3968
#define KDIM 1024

typedef __attribute__((ext_vector_type(8))) short short8;
typedef __attribute__((ext_vector_type(4))) float floatx4;
typedef unsigned short ushort_t;

__device__ inline unsigned short f2bf(float x) {
    union { float f; unsigned u; } v; v.f = x;
    unsigned r = v.u + 0x7fffu + ((v.u >> 16) & 1u);   // RNE
    return (unsigned short)(r >> 16);
}

__device__ inline float bf2f(ushort_t u) {
    union { unsigned u; float f; } v; v.u = ((unsigned)u) << 16; return v.f;
}

__device__ inline uint4 pack8(float4 a, float4 b) {
    union { unsigned short us[8]; uint4 u4; } p;
    p.us[0]=f2bf(a.x); p.us[1]=f2bf(a.y); p.us[2]=f2bf(a.z); p.us[3]=f2bf(a.w);
    p.us[4]=f2bf(b.x); p.us[5]=f2bf(b.y); p.us[6]=f2bf(b.z); p.us[7]=f2bf(b.w);
    return p.u4;
}

__device__ inline float4 add4(float4 a, float4 b) {
    float4 r; r.x=a.x+b.x; r.y=a.y+b.y; r.z=a.z+b.z; r.w=a.w+b.w; return r;
}

#define GLOAD_LDS16(g, l) \
    __builtin_amdgcn_global_load_lds((__attribute__((address_space(1))) const void*)(g), \
                                     (__attribute__((address_space(3))) void*)(l), 16, 0, 0)

// =======================================================================
// K1: QKV GEMM with inline fp32->bf16 staging.
// Pq[z][512][3072] += Xslice(bf16) @ [Wq|Wk|Wv](bf16)^T  (split-K z=0,1)
// grid = 768 = 48(n) x 8(m) x 2(ks). Reg-staged at the SAME pre-swizzled
// addresses the verified global_load_lds path used -> identical LDS image.
// =======================================================================
__global__ __launch_bounds__(256) void qkv_gemm(const float* __restrict__ in,
                                                const float* __restrict__ Wq,
                                                const float* __restrict__ Wk,
                                                const float* __restrict__ Wv,
                                                float* __restrict__ Pq) {
    __shared__ ushort_t As[64][64];
    __shared__ ushort_t Bs[64][64];
    int bid = blockIdx.x;
    int z = bid / 384;
    int rem = bid - z * 384;
    int x = rem % 48, y = rem / 48;
    int m0 = y * 64, n0 = x * 64, koff = z * 512;
    const float* Wsrc = (n0 < 1024) ? Wq : (n0 < 2048) ? Wk : Wv;
    int nrow0 = n0 & 1023;

    int tid = threadIdx.x;
    int lane = tid & 63, w = tid >> 6;
    int r0 = tid >> 3, g0 = (tid & 7) ^ (r0 & 7);
    int r1 = r0 + 32,  g1 = (tid & 7) ^ (r1 & 7);

    int am0 = m0 + r0, am1 = m0 + r1;
    const float* gaA0 = in + (size_t)((am0 >> 7) * S_ + CSTART + (am0 & 127)) * H_ + koff + g0 * 8;
    const float* gaA1 = in + (size_t)((am1 >> 7) * S_ + CSTART + (am1 & 127)) * H_ + koff + g1 * 8;
    const float* gaB0 = Wsrc + (size_t)(nrow0 + r0) * 1024 + koff + g0 * 8;
    const float* gaB1 = Wsrc + (size_t)(nrow0 + r1) * 1024 + koff + g1 * 8;
    uint4* lsA0 = (uint4*)((char*)As + tid * 16);
    uint4* lsA1 = (uint4*)((char*)As + tid * 16 + 4096);
    uint4* lsB0 = (uint4*)((char*)Bs + tid * 16);
    uint4* lsB1 = (uint4*)((char*)Bs + tid * 16 + 4096);

    int fm = lane & 15, q = lane >> 4;
    int wr = w >> 1, wc = w & 1;
    int ma0 = wr * 32, na0 = wc * 32;
    floatx4 acc[2][2] = {};

    float4 ra0, ra1, ra2, ra3, rb0, rb1, rb2, rb3;
#define LOAD_REGS_K1(k) do { \
        ra0 = *(const float4*)(gaA0 + (k));     ra1 = *(const float4*)(gaA0 + (k) + 4); \
        ra2 = *(const float4*)(gaA1 + (k));     ra3 = *(const float4*)(gaA1 + (k) + 4); \
        rb0 = *(const float4*)(gaB0 + (k));     rb1 = *(const float4*)(gaB0 + (k) + 4); \
        rb2 = *(const float4*)(gaB1 + (k));     rb3 = *(const float4*)(gaB1 + (k) + 4); } while (0)

    LOAD_REGS_K1(0);
    for (int k0 = 0; k0 < 512; k0 += 64) {
        uint4 pa0 = pack8(ra0, ra1), pa1 = pack8(ra2, ra3);
        uint4 pb0 = pack8(rb0, rb1), pb1 = pack8(rb2, rb3);
        if (k0) __syncthreads();          // prior MFMA reads done before overwrite
        *lsA0 = pa0; *lsA1 = pa1; *lsB0 = pb0; *lsB1 = pb1;
        __syncthreads();
        if (k0 + 64 < 512) LOAD_REGS_K1(k0 + 64);   // overlap with MFMA phase
        #pragma unroll
        for (int kb = 0; kb < 2; kb++) {
            short8 af[2], bfr[2];
            #pragma unroll
            for (int t = 0; t < 2; t++) {
                int m = ma0 + t * 16 + fm;
                int pa = (kb * 4 + q) ^ (m & 7);
                af[t] = *(const short8*)(&As[m][pa * 8]);
                int n = na0 + t * 16 + fm;
                int pb = (kb * 4 + q) ^ (n & 7);
                bfr[t] = *(const short8*)(&Bs[n][pb * 8]);
            }
            #pragma unroll
            for (int i = 0; i < 2; i++)
                #pragma unroll
                for (int j = 0; j < 2; j++)
                    acc[i][j] = __builtin_amdgcn_mfma_f32_16x16x32_bf16(af[i], bfr[j], acc[i][j], 0, 0, 0);
        }
    }
    float* outp = Pq + (size_t)z * 512 * 3072;
    #pragma unroll
    for (int i = 0; i < 2; i++)
        #pragma unroll
        for (int j = 0; j < 2; j++) {
            int row = m0 + ma0 + i * 16 + q * 4;
            int col = n0 + na0 + j * 16 + fm;
            #pragma unroll
            for (int t = 0; t < 4; t++)
                outp[(size_t)(row + t) * 3072 + col] = acc[i][j][t];
        }
}

// =======================================================================
// K2: MFMA attention (verified body, unchanged): block = (b, h, half)
// =======================================================================
__global__ __launch_bounds__(256) void attn(const float* __restrict__ Pq,   // [2][512][3072]
                                            const int* __restrict__ amask,
                                            ushort_t* __restrict__ AO) {
    __shared__ __align__(16) char smem[46080];
    ushort_t* Qs   = (ushort_t*)(smem);             // [64][72]
    ushort_t* Ksh  = (ushort_t*)(smem + 9216);      // [128][72]
    ushort_t* Pb   = (ushort_t*)(smem);             // overlay, [64][136]
    float*    linv = (float*)(smem + 27648);        // [64]
    int*      amk  = (int*)(smem + 27904);          // [128]
    ushort_t* Vt   = (ushort_t*)(smem + 28416);     // [64][136]

    int gid = blockIdx.x;
    int b = gid >> 5, h = (gid >> 1) & 15, half = gid & 1;
    int tid = threadIdx.x;
    int cmax = half ? CTX : 64;
    {
        int r = tid >> 2, ch = tid & 3;
        size_t qb = (size_t)(b * CTX + half * 64 + r) * 3072 + h * 64 + ch * 16;
        const float4* q0 = (const float4*)(Pq + qb);
        const float4* q1 = (const float4*)(Pq + (size_t)512 * 3072 + qb);
        float4 a0 = add4(q0[0], q1[0]), a1 = add4(q0[1], q1[1]);
        float4 a2 = add4(q0[2], q1[2]), a3 = add4(q0[3], q1[3]);
        *(uint4*)(Qs + r * 72 + ch * 16)     = pack8(a0, a1);
        *(uint4*)(Qs + r * 72 + ch * 16 + 8) = pack8(a2, a3);
        for (int idx = tid; idx < cmax * 4; idx += 256) {
            int kr = idx >> 2, kch = idx & 3;
            size_t base = (size_t)(b * CTX + kr) * 3072 + h * 64 + kch * 16;
            const float4* p0 = (const float4*)(Pq + base);
            const float4* p1 = (const float4*)(Pq + (size_t)512 * 3072 + base);
            float4 k0 = add4(p0[256], p1[256]), k1 = add4(p0[257], p1[257]);
            float4 k2 = add4(p0[258], p1[258]), k3 = add4(p0[259], p1[259]);
            *(uint4*)(Ksh + kr * 72 + kch * 16)     = pack8(k0, k1);
            *(uint4*)(Ksh + kr * 72 + kch * 16 + 8) = pack8(k2, k3);
            float vv[16];
            #pragma unroll
            for (int c4 = 0; c4 < 4; c4++) {
                float4 s = add4(p0[512 + c4], p1[512 + c4]);
                vv[c4*4+0]=s.x; vv[c4*4+1]=s.y; vv[c4*4+2]=s.z; vv[c4*4+3]=s.w;
            }
            #pragma unroll
            for (int i = 0; i < 16; i++)
                Vt[(kch * 16 + i) * 136 + kr] = f2bf(vv[i]);
        }
        if (tid < 128) amk[tid] = amask[b * S_ + CSTART + tid];
    }
    __syncthreads();

    int w = tid >> 6, lane = tid & 63;
    int qt = half * 4 + w;
    int lr0 = w * 16;
    int fm = lane & 15, quad = lane >> 4;

    short8 af[2];
    #pragma unroll
    for (int kb = 0; kb < 2; kb++)
        af[kb] = *(const short8*)(Qs + (lr0 + fm) * 72 + kb * 32 + quad * 8);
    floatx4 acc[8] = {};
    for (int ct = 0; ct <= qt; ct++) {
        #pragma unroll
        for (int kb = 0; kb < 2; kb++) {
            short8 bfr = *(const short8*)(Ksh + (ct * 16 + fm) * 72 + kb * 32 + quad * 8);
            acc[ct] = __builtin_amdgcn_mfma_f32_16x16x32_bf16(af[kb], bfr, acc[ct], 0, 0, 0);
        }
    }
    int myamk[8];
    #pragma unroll
    for (int ct = 0; ct < 8; ct++) myamk[ct] = amk[ct * 16 + fm];
    float ls[4];
    #pragma unroll
    for (int t = 0; t < 4; t++) {
        int row = qt * 16 + quad * 4 + t;
        float m = -INFINITY;
        #pragma unroll
        for (int ct = 0; ct < 8; ct++) {
            int col = ct * 16 + fm;
            float s = acc[ct][t] * 0.125f;
            bool valid = (ct <= qt) && (col <= row) && (myamk[ct] != 0);
            if (valid) m = fmaxf(m, s);
        }
        #pragma unroll
        for (int off = 8; off >= 1; off >>= 1) m = fmaxf(m, __shfl_xor(m, off, 64));
        float l = 0.f;
        #pragma unroll
        for (int ct = 0; ct < 8; ct++) {
            int col = ct * 16 + fm;
            float s = acc[ct][t] * 0.125f;
            bool valid = (ct <= qt) && (col <= row) && (myamk[ct] != 0);
            float p = valid ? __expf(s - m) : 0.f;
            acc[ct][t] = p;
            l += p;
        }
        #pragma unroll
        for (int off = 8; off >= 1; off >>= 1) l += __shfl_xor(l, off, 64);
        ls[t] = l;
    }
    __syncthreads();
    #pragma unroll
    for (int t = 0; t < 4; t++) {
        int lrow = lr0 + quad * 4 + t;
        #pragma unroll
        for (int ct = 0; ct < 8; ct++)
            Pb[lrow * 136 + ct * 16 + fm] = f2bf(acc[ct][t]);
        if (fm == 0) linv[lrow] = 1.f / ls[t];
    }
    int kmax = (qt >> 1) + 1;
    floatx4 oacc[4] = {};
    for (int kb = 0; kb < kmax; kb++) {
        short8 paf = *(const short8*)(Pb + (lr0 + fm) * 136 + kb * 32 + quad * 8);
        #pragma unroll
        for (int dt = 0; dt < 4; dt++) {
            short8 vbf = *(const short8*)(Vt + (dt * 16 + fm) * 136 + kb * 32 + quad * 8);
            oacc[dt] = __builtin_amdgcn_mfma_f32_16x16x32_bf16(paf, vbf, oacc[dt], 0, 0, 0);
        }
    }
    #pragma unroll
    for (int t = 0; t < 4; t++) {
        int lrow = lr0 + quad * 4 + t;
        int grow = qt * 16 + quad * 4 + t;
        float inv = linv[lrow];
        #pragma unroll
        for (int dt = 0; dt < 4; dt++)
            AO[(size_t)(b * CTX + grow) * H_ + h * 64 + dt * 16 + fm] = f2bf(oacc[dt][t] * inv);
    }
}

// =======================================================================
// K3: blocks 0..127  : O-GEMM (A=AObf bf16 via global_load_lds, B=Wo fp32
//                      reg-staged), K=1024, direct-store to out rows
//                      CSTART..4095 of each batch.
//     blocks 128..639: broadcast — each block redundantly computes its
//                      64-col slice of AO[b*128] @ Wo^T (fp32 dot) and
//                      writes 496 identical rows (rows 0..CSTART-1).
// =======================================================================
__global__ __launch_bounds__(256) void ogemm_bcast(const ushort_t* __restrict__ AObf,
                                                   const float* __restrict__ Wo,
                                                   float* __restrict__ out) {
    __shared__ __align__(16) char smem[16384];
    int bid = blockIdx.x;
    int tid = threadIdx.x;

    if (bid < 128) {
        ushort_t (*As)[64] = (ushort_t(*)[64])smem;
        ushort_t (*Bs)[64] = (ushort_t(*)[64])(smem + 8192);
        int x = bid % 16, y = bid / 16;
        int m0 = y * 64, n0 = x * 64;
        int lane = tid & 63, w = tid >> 6;
        int r0 = tid >> 3, g0 = (tid & 7) ^ (r0 & 7);
        int r1 = r0 + 32,  g1 = (tid & 7) ^ (r1 & 7);
        const ushort_t* ga0 = AObf + (size_t)(m0 + r0) * KDIM + g0 * 8;
        const ushort_t* ga1 = AObf + (size_t)(m0 + r1) * KDIM + g1 * 8;
        const float*    gb0 = Wo + (size_t)(n0 + r0) * 1024 + g0 * 8;
        const float*    gb1 = Wo + (size_t)(n0 + r1) * 1024 + g1 * 8;
        char* laA0 = smem + tid * 16;
        char* laA1 = smem + tid * 16 + 4096;
        uint4* lsB0 = (uint4*)(smem + 8192 + tid * 16);
        uint4* lsB1 = (uint4*)(smem + 8192 + tid * 16 + 4096);

        int fm = lane & 15, q = lane >> 4;
        int wr = w >> 1, wc = w & 1;
        int ma0 = wr * 32, na0 = wc * 32;
        floatx4 acc[2][2] = {};

        float4 rb0, rb1, rb2, rb3;
#define LOAD_REGS_K3(k) do { \
            rb0 = *(const float4*)(gb0 + (k)); rb1 = *(const float4*)(gb0 + (k) + 4); \
            rb2 = *(const float4*)(gb1 + (k)); rb3 = *(const float4*)(gb1 + (k) + 4); } while (0)

        LOAD_REGS_K3(0);
        for (int k0 = 0; k0 < 1024; k0 += 64) {
            uint4 pb0 = pack8(rb0, rb1), pb1 = pack8(rb2, rb3);
            if (k0) __syncthreads();          // prior reads done before overwrite
            GLOAD_LDS16(ga0 + k0, laA0);
            GLOAD_LDS16(ga1 + k0, laA1);
            *lsB0 = pb0; *lsB1 = pb1;
            __syncthreads();
            if (k0 + 64 < 1024) LOAD_REGS_K3(k0 + 64);
            #pragma unroll
            for (int kb = 0; kb < 2; kb++) {
                short8 af[2], bfr[2];
                #pragma unroll
                for (int t = 0; t < 2; t++) {
                    int m = ma0 + t * 16 + fm;
                    int pa = (kb * 4 + q) ^ (m & 7);
                    af[t] = *(const short8*)(&As[m][pa * 8]);
                    int n = na0 + t * 16 + fm;
                    int pb = (kb * 4 + q) ^ (n & 7);
                    bfr[t] = *(const short8*)(&Bs[n][pb * 8]);
                }
                #pragma unroll
                for (int i = 0; i < 2; i++)
                    #pragma unroll
                    for (int j = 0; j < 2; j++)
                        acc[i][j] = __builtin_amdgcn_mfma_f32_16x16x32_bf16(af[i], bfr[j], acc[i][j], 0, 0, 0);
            }
        }
        #pragma unroll
        for (int i = 0; i < 2; i++)
            #pragma unroll
            for (int j = 0; j < 2; j++) {
                int row = m0 + ma0 + i * 16 + q * 4;
                int col = n0 + na0 + j * 16 + fm;
                #pragma unroll
                for (int t = 0; t < 4; t++) {
                    int rr = row + t;
                    size_t gr = (size_t)((rr >> 7) * S_ + CSTART + (rr & 127));
                    out[gr * 1024 + col] = acc[i][j][t];
                }
            }
    } else {
        // -------- broadcast blocks --------
        float* vals = (float*)smem;            // [64]
        int idx = bid - 128;                   // 0..511
        int c  = idx & 15;                     // col block (64 cols)
        int b2 = (idx >> 4) & 3;               // batch
        int rc = idx >> 6;                     // 0..7 row chunk (496 rows)
        int n0 = c * 64;
        int w = tid >> 6, lane = tid & 63;
        int rsub = lane >> 4, kl = lane & 15;
        const ushort_t* ao = AObf + (size_t)(b2 * 128) * 1024;
        #pragma unroll
        for (int p = 0; p < 4; p++) {
            int rl = p * 16 + w * 4 + rsub;    // local col 0..63
            const float* wrow = Wo + (size_t)(n0 + rl) * 1024;
            float4 av = {0.f, 0.f, 0.f, 0.f};
            #pragma unroll
            for (int it = 0; it < 16; it++) {
                int k = kl * 4 + it * 64;
                float4 wv = *(const float4*)(wrow + k);
                av.x += wv.x * bf2f(ao[k]);
                av.y += wv.y * bf2f(ao[k + 1]);
                av.z += wv.z * bf2f(ao[k + 2]);
                av.w += wv.w * bf2f(ao[k + 3]);
            }
            float s = av.x + av.y + av.z + av.w;
            #pragma unroll
            for (int off = 1; off < 16; off <<= 1) s += __shfl_xor(s, off, 64);
            if (kl == 0) vals[rl] = s;
        }
        __syncthreads();
        int c4 = tid & 15, ro = tid >> 4;
        float4 v4 = *(const float4*)(vals + c4 * 4);
        size_t gbase = (size_t)b2 * S_ * 1024 + n0 + c4 * 4;
        #pragma unroll
        for (int i = 0; i < 31; i++) {
            int p = rc * 496 + ro + i * 16;    // 0..3967
            *(float4*)(out + gbase + (size_t)p * 1024) = v4;
        }
    }
}

extern "C" void kernel_launch(void* const* d_in, const int* in_sizes, int n_in,
                              void* d_out, int out_size, void* d_ws, size_t ws_size,
                              hipStream_t stream) {
    const float* inputs = (const float*)d_in[0];
    const int*   amask  = (const int*)d_in[1];
    const float* Wq     = (const float*)d_in[2];
    const float* Wk     = (const float*)d_in[3];
    const float* Wv     = (const float*)d_in[4];
    const float* Wo     = (const float*)d_in[5];
    float* out = (float*)d_out;

    char* ws = (char*)d_ws;
    float*    Pq   = (float*)(ws);                    // 12.6 MB [2][512][3072] fp32
    ushort_t* AObf = (ushort_t*)(ws + (13u << 20));   // 1 MB [512][1024] bf16

    qkv_gemm<<<768, 256, 0, stream>>>(inputs, Wq, Wk, Wv, Pq);
    attn<<<128, 256, 0, stream>>>(Pq, amask, AObf);
    ogemm_bcast<<<640, 256, 0, stream>>>(AObf, Wo, out);
}